// Round 4
// baseline (909.956 us; speedup 1.0000x reference)
//
#include <hip/hip_runtime.h>
#include <hip/hip_bf16.h>

// StructureBuilder: masked patch-correlation attention. FP32 I/O (per reference
// dtypes), f16 internal patch banks + MFMA.
//   prep: conv1x1+inorm+relu -> q_act/k_act f16 images; vbar = tap-mean of V
//   zero: att = 0
//   attn: per (64-pixel row tile, head): flash attention, 16x16x32 f16 MFMA,
//         K patch tile built in LDS from k_act each key-tile; atomicAdd head-mean
//   out:  Wo conv + inorm + relu -> fp32

#define LL 4096          // H*W
#define CC 64            // channels
#define AA 128           // attention channels
#define NH_ 8            // heads
#define DD 160           // patch depth 144 padded to 160
#define BSTR 168         // LDS row stride for Bk (21 x 16B)
#define VSTR 72          // LDS row stride for Vt/Pb (9 x 16B)

typedef _Float16 half8 __attribute__((ext_vector_type(8)));
typedef float floatx4 __attribute__((ext_vector_type(4)));

// ---------------- K1: conv1x1 + inorm + relu -> activation images; vbar ----------------
__global__ __launch_bounds__(256) void prep_kernel(
    const float* __restrict__ feat,
    const float* __restrict__ masks,
    const float* __restrict__ Wq, const float* __restrict__ bq,
    const float* __restrict__ Wk, const float* __restrict__ bk,
    _Float16* __restrict__ q_act, _Float16* __restrict__ k_act,
    _Float16* __restrict__ vb)
{
    const int tid = threadIdx.x;
    const int b = blockIdx.x;
    __shared__ float sW[CC];
    __shared__ float sm[8];

    if (b >= 2 * AA) {
        // vbar[c][l] = (1/9) sum_taps f_unmasked[c, l + shift_t]  (OOB = 0)
        int c = b - 2 * AA;
        for (int p = 0; p < 16; ++p) {
            int l = p * 256 + tid;
            int y = l >> 6, x = l & 63;
            float s = 0.f;
            for (int ty = 0; ty < 3; ++ty) {
                int yy = y + 2 * (ty - 1);
                if (yy < 0 || yy > 63) continue;
                for (int tx = 0; tx < 3; ++tx) {
                    int xx = x + 2 * (tx - 1);
                    if (xx < 0 || xx > 63) continue;
                    int ll = yy * 64 + xx;
                    float hole = masks[ll] > 0.5f ? 1.f : 0.f;
                    s += feat[c * LL + ll] * (1.f - hole);
                }
            }
            vb[c * LL + l] = (_Float16)(s * (1.f / 9.f));
        }
        return;
    }

    const int a = b & (AA - 1);
    const int sel = b >> 7;  // 0 = q (hole pixels), 1 = k (unmasked pixels)
    const float* Wrow = (sel ? Wk : Wq) + a * CC;
    const float bias = sel ? bk[a] : bq[a];
    if (tid < CC) sW[tid] = Wrow[tid];
    __syncthreads();

    float vals[16];
    float s1 = 0.f, s2 = 0.f;
    for (int p = 0; p < 16; ++p) {
        int l = p * 256 + tid;
        float hole = masks[l] > 0.5f ? 1.f : 0.f;
        float mf = sel ? (1.f - hole) : hole;
        float acc = 0.f;
        for (int c = 0; c < CC; ++c)
            acc += sW[c] * feat[c * LL + l];
        acc = acc * mf + bias;
        vals[p] = acc; s1 += acc; s2 += acc * acc;
    }
    for (int off = 32; off; off >>= 1) {
        s1 += __shfl_down(s1, off, 64);
        s2 += __shfl_down(s2, off, 64);
    }
    int wv = tid >> 6, ln = tid & 63;
    if (ln == 0) { sm[wv * 2] = s1; sm[wv * 2 + 1] = s2; }
    __syncthreads();
    s1 = sm[0] + sm[2] + sm[4] + sm[6];
    s2 = sm[1] + sm[3] + sm[5] + sm[7];
    float mu = s1 * (1.f / LL);
    float inv = rsqrtf(s2 * (1.f / LL) - mu * mu + 1e-5f);

    _Float16* act = (sel ? k_act : q_act) + (size_t)a * LL;
    for (int p = 0; p < 16; ++p) {
        int l = p * 256 + tid;
        float v = (vals[p] - mu) * inv;
        act[l] = (_Float16)(v > 0.f ? v : 0.f);
    }
}

// ---------------- K2: zero att accumulator ----------------
__global__ __launch_bounds__(256) void zero_att(float* __restrict__ att)
{
    int idx = blockIdx.x * 256 + threadIdx.x;
    att[idx] = 0.f;
}

// ---------------- K3: flash patch-correlation attention ----------------
// grid = (64 pixel-row tiles, 8 heads), 256 threads (4 waves);
// wave w owns query pixels x in [16w, 16w+16) of image row y = qt.
__global__ __launch_bounds__(256) void attn_kernel(
    const _Float16* __restrict__ q_act, const _Float16* __restrict__ k_act,
    const _Float16* __restrict__ vb, float* __restrict__ att)
{
    const int qt = blockIdx.x, n = blockIdx.y;
    const int i0 = qt * 64;
    const int tid = threadIdx.x;
    const int w = tid >> 6, lane = tid & 63;
    const int l15 = lane & 15, quad = lane >> 4;

    __shared__ __align__(16) _Float16 Bk[64 * BSTR];    // 21504 B
    __shared__ __align__(16) _Float16 Vt[64 * VSTR];    //  9216 B
    __shared__ __align__(16) _Float16 Pb[4][16 * VSTR]; //  9216 B

    const _Float16* qa = q_act + (size_t)n * 16 * LL;
    const _Float16* ka = k_act + (size_t)n * 16 * LL;

    // A-fragments: query pixel (y=qt, x=w*16+l15), d-slice ks*32 + quad*8 (+j)
    half8 afrag[5];
    {
        const int x = w * 16 + l15;
#pragma unroll
        for (int ks = 0; ks < 5; ++ks) {
#pragma unroll
            for (int j = 0; j < 8; ++j) {
                int d = ks * 32 + quad * 8 + j;
                _Float16 v = (_Float16)0.f;
                if (d < 144) {
                    int ah = d / 9, t = d - ah * 9;
                    int ty = t / 3, tx = t - ty * 3;
                    int yy = qt + 2 * (ty - 1);
                    int xx = x + 2 * (tx - 1);
                    if (yy >= 0 && yy <= 63 && xx >= 0 && xx <= 63)
                        v = qa[ah * LL + yy * 64 + xx];
                }
                afrag[ks][j] = v;
            }
        }
    }

    floatx4 accO[4];
    float mrow[4], lrow[4];
#pragma unroll
    for (int i = 0; i < 4; ++i) {
        accO[i] = (floatx4){0.f, 0.f, 0.f, 0.f};
        mrow[i] = -1e30f; lrow[i] = 0.f;
    }

    for (int jt = 0; jt < 64; ++jt) {
        __syncthreads();  // previous iteration's Bk/Vt reads complete
        // build Bk[key x][d] for key image row y=jt, gathered from k_act
        for (int e = tid; e < 64 * DD; e += 256) {
            int x = e / DD, d = e - x * DD;
            _Float16 v = (_Float16)0.f;
            if (d < 144) {
                int ah = d / 9, t = d - ah * 9;
                int ty = t / 3, tx = t - ty * 3;
                int yy = jt + 2 * (ty - 1);
                int xx = x + 2 * (tx - 1);
                if (yy >= 0 && yy <= 63 && xx >= 0 && xx <= 63)
                    v = ka[ah * LL + yy * 64 + xx];
            }
            Bk[x * BSTR + d] = v;
        }
        {   // stage Vt: channels x 64 keys of this tile
            const uint4* vsrc = (const uint4*)vb;
            uint4* vdst = (uint4*)Vt;
            for (int t = tid; t < 512; t += 256) {
                int c = t >> 3, e = t & 7;
                vdst[c * 9 + e] = vsrc[c * (LL / 8) + jt * 8 + e];
            }
        }
        __syncthreads();

        // S tile: wave's 16 query pixels x 64 keys, K = 160 (tail zero)
        floatx4 accS[4];
#pragma unroll
        for (int i = 0; i < 4; ++i) accS[i] = (floatx4){0.f, 0.f, 0.f, 0.f};
        for (int ks = 0; ks < 5; ++ks) {
#pragma unroll
            for (int nt = 0; nt < 4; ++nt) {
                half8 bfr = *(const half8*)(Bk + (nt * 16 + l15) * BSTR + ks * 32 + quad * 8);
                accS[nt] = __builtin_amdgcn_mfma_f32_16x16x32_f16(afrag[ks], bfr, accS[nt], 0, 0, 0);
            }
        }

        // online softmax; D-layout: row = quad*4+r, col = l15
#pragma unroll
        for (int r = 0; r < 4; ++r) {
            float tm = fmaxf(fmaxf(accS[0][r], accS[1][r]), fmaxf(accS[2][r], accS[3][r]));
#pragma unroll
            for (int off = 8; off; off >>= 1) tm = fmaxf(tm, __shfl_xor(tm, off, 16));
            float mn = fmaxf(mrow[r], tm);
            float alpha = __expf(mrow[r] - mn);
            mrow[r] = mn;
            float rs = 0.f;
#pragma unroll
            for (int nt = 0; nt < 4; ++nt) {
                float pv = __expf(accS[nt][r] - mn);
                accS[nt][r] = pv;
                rs += pv;
            }
#pragma unroll
            for (int off = 8; off; off >>= 1) rs += __shfl_xor(rs, off, 16);
            lrow[r] = lrow[r] * alpha + rs;
#pragma unroll
            for (int nt = 0; nt < 4; ++nt) accO[nt][r] *= alpha;
        }

        // P: C-layout -> A-layout round trip via per-wave LDS buffer
        _Float16* pw = Pb[w];
#pragma unroll
        for (int nt = 0; nt < 4; ++nt)
#pragma unroll
            for (int r = 0; r < 4; ++r)
                pw[(quad * 4 + r) * VSTR + nt * 16 + l15] = (_Float16)accS[nt][r];
        __syncthreads();

        // O += P @ Vt^T  (K = 64 keys, N = 64 channels)
#pragma unroll
        for (int ks = 0; ks < 2; ++ks) {
            half8 afr = *(const half8*)(pw + l15 * VSTR + ks * 32 + quad * 8);
#pragma unroll
            for (int nt = 0; nt < 4; ++nt) {
                half8 bfr = *(const half8*)(Vt + (nt * 16 + l15) * VSTR + ks * 32 + quad * 8);
                accO[nt] = __builtin_amdgcn_mfma_f32_16x16x32_f16(afr, bfr, accO[nt], 0, 0, 0);
            }
        }
    }

    // head-mean accumulate: att[l][c] += O[l][c]/lrow/8
#pragma unroll
    for (int r = 0; r < 4; ++r) {
        float sc = 0.125f / lrow[r];
        int l = i0 + w * 16 + quad * 4 + r;
#pragma unroll
        for (int nt = 0; nt < 4; ++nt)
            atomicAdd(att + (size_t)l * CC + nt * 16 + l15, accO[nt][r] * sc);
    }
}

// ---------------- K4: Wo conv + inorm + relu ----------------
__global__ __launch_bounds__(256) void out_kernel(
    const float* __restrict__ att,
    const float* __restrict__ Wo, const float* __restrict__ bo,
    float* __restrict__ out)
{
    const int o = blockIdx.x;
    const int tid = threadIdx.x;
    __shared__ float sW[CC];
    __shared__ float sm[8];
    if (tid < CC) sW[tid] = Wo[o * CC + tid];
    __syncthreads();
    const float bias = bo[o];

    float vals[16], s1 = 0.f, s2 = 0.f;
    for (int p = 0; p < 16; ++p) {
        int l = p * 256 + tid;
        const float4* arow = (const float4*)(att + (size_t)l * CC);
        float acc = bias;
#pragma unroll
        for (int c4 = 0; c4 < 16; ++c4) {
            float4 a4 = arow[c4];
            acc += sW[c4 * 4] * a4.x + sW[c4 * 4 + 1] * a4.y +
                   sW[c4 * 4 + 2] * a4.z + sW[c4 * 4 + 3] * a4.w;
        }
        vals[p] = acc; s1 += acc; s2 += acc * acc;
    }
    for (int off = 32; off; off >>= 1) {
        s1 += __shfl_down(s1, off, 64);
        s2 += __shfl_down(s2, off, 64);
    }
    int wv = tid >> 6, ln = tid & 63;
    if (ln == 0) { sm[wv * 2] = s1; sm[wv * 2 + 1] = s2; }
    __syncthreads();
    s1 = sm[0] + sm[2] + sm[4] + sm[6];
    s2 = sm[1] + sm[3] + sm[5] + sm[7];
    float mu = s1 * (1.f / LL);
    float inv = rsqrtf(s2 * (1.f / LL) - mu * mu + 1e-5f);
    for (int p = 0; p < 16; ++p) {
        int l = p * 256 + tid;
        float v = (vals[p] - mu) * inv;
        out[(size_t)o * LL + l] = v > 0.f ? v : 0.f;
    }
}

extern "C" void kernel_launch(void* const* d_in, const int* in_sizes, int n_in,
                              void* d_out, int out_size, void* d_ws, size_t ws_size,
                              hipStream_t stream) {
    const float* feat  = (const float*)d_in[0];
    const float* masks = (const float*)d_in[1];
    const float* Wq    = (const float*)d_in[2];
    const float* bq    = (const float*)d_in[3];
    const float* Wk    = (const float*)d_in[4];
    const float* bk    = (const float*)d_in[5];
    const float* Wo    = (const float*)d_in[6];
    const float* bo    = (const float*)d_in[7];
    float* out = (float*)d_out;

    char* ws = (char*)d_ws;
    // layout (bytes) — total 3,670,016 (~3.5 MB):
    //   q_act f16 [128][4096] @ 0           (1,048,576)
    //   k_act f16 [128][4096] @ 1,048,576   (1,048,576)
    //   vb    f16 [64][4096]  @ 2,097,152   (  524,288)
    //   att   f32 [4096][64]  @ 2,621,440   (1,048,576)
    _Float16* q_act = (_Float16*)ws;
    _Float16* k_act = (_Float16*)(ws + 1048576);
    _Float16* vb    = (_Float16*)(ws + 2097152);
    float*    att   = (float*)(ws + 2621440);

    prep_kernel<<<2 * AA + CC, 256, 0, stream>>>(feat, masks, Wq, bq, Wk, bk,
                                                 q_act, k_act, vb);
    zero_att<<<LL * CC / 256, 256, 0, stream>>>(att);
    dim3 g(64, NH_);
    attn_kernel<<<g, 256, 0, stream>>>(q_act, k_act, vb, att);
    out_kernel<<<CC, 256, 0, stream>>>(att, Wo, bo, out);
}

// Round 5
// 551.774 us; speedup vs baseline: 1.6491x; 1.6491x over previous
//
#include <hip/hip_runtime.h>
#include <hip/hip_bf16.h>

// StructureBuilder: masked patch-correlation attention. FP32 I/O, f16 internal.
//   prep:     conv1x1+inorm+relu -> q_act/k_act f16 images; vbar = tap-mean of V
//   build_kp: materialize K patch bank once (f16 [8][4096][160])
//   zero:     att = 0
//   attn:     flash attention per (head, 64-pixel row tile); 16x16x32 f16 MFMA;
//             double-buffered vectorized Bk/Vt staging with register prefetch
//   out:      Wo conv + inorm + relu -> fp32

#define LL 4096          // H*W
#define CC 64            // channels
#define AA 128           // attention channels
#define NH_ 8            // heads
#define DD 160           // patch depth 144 padded to 160
#define BSTR 168         // LDS row stride for Bk (21 x 16B: 2-way bank aliasing = free)
#define VSTR 72          // LDS row stride for Vt/Pb (9 x 16B)

typedef _Float16 half8 __attribute__((ext_vector_type(8)));
typedef float floatx4 __attribute__((ext_vector_type(4)));

// ---------------- K1: conv1x1 + inorm + relu -> activation images; vbar ----------------
__global__ __launch_bounds__(256) void prep_kernel(
    const float* __restrict__ feat,
    const float* __restrict__ masks,
    const float* __restrict__ Wq, const float* __restrict__ bq,
    const float* __restrict__ Wk, const float* __restrict__ bk,
    _Float16* __restrict__ q_act, _Float16* __restrict__ k_act,
    _Float16* __restrict__ vb)
{
    const int tid = threadIdx.x;
    const int b = blockIdx.x;
    __shared__ float sW[CC];
    __shared__ float sm[8];

    if (b >= 2 * AA) {
        // vbar[c][l] = (1/9) sum_taps f_unmasked[c, l + shift_t]  (OOB = 0)
        int c = b - 2 * AA;
        for (int p = 0; p < 16; ++p) {
            int l = p * 256 + tid;
            int y = l >> 6, x = l & 63;
            float s = 0.f;
            for (int ty = 0; ty < 3; ++ty) {
                int yy = y + 2 * (ty - 1);
                if (yy < 0 || yy > 63) continue;
                for (int tx = 0; tx < 3; ++tx) {
                    int xx = x + 2 * (tx - 1);
                    if (xx < 0 || xx > 63) continue;
                    int ll = yy * 64 + xx;
                    float hole = masks[ll] > 0.5f ? 1.f : 0.f;
                    s += feat[c * LL + ll] * (1.f - hole);
                }
            }
            vb[c * LL + l] = (_Float16)(s * (1.f / 9.f));
        }
        return;
    }

    const int a = b & (AA - 1);
    const int sel = b >> 7;  // 0 = q (hole pixels), 1 = k (unmasked pixels)
    const float* Wrow = (sel ? Wk : Wq) + a * CC;
    const float bias = sel ? bk[a] : bq[a];
    if (tid < CC) sW[tid] = Wrow[tid];
    __syncthreads();

    float vals[16];
    float s1 = 0.f, s2 = 0.f;
    for (int p = 0; p < 16; ++p) {
        int l = p * 256 + tid;
        float hole = masks[l] > 0.5f ? 1.f : 0.f;
        float mf = sel ? (1.f - hole) : hole;
        float acc = 0.f;
        for (int c = 0; c < CC; ++c)
            acc += sW[c] * feat[c * LL + l];
        acc = acc * mf + bias;
        vals[p] = acc; s1 += acc; s2 += acc * acc;
    }
    for (int off = 32; off; off >>= 1) {
        s1 += __shfl_down(s1, off, 64);
        s2 += __shfl_down(s2, off, 64);
    }
    int wv = tid >> 6, ln = tid & 63;
    if (ln == 0) { sm[wv * 2] = s1; sm[wv * 2 + 1] = s2; }
    __syncthreads();
    s1 = sm[0] + sm[2] + sm[4] + sm[6];
    s2 = sm[1] + sm[3] + sm[5] + sm[7];
    float mu = s1 * (1.f / LL);
    float inv = rsqrtf(s2 * (1.f / LL) - mu * mu + 1e-5f);

    _Float16* act = (sel ? k_act : q_act) + (size_t)a * LL;
    for (int p = 0; p < 16; ++p) {
        int l = p * 256 + tid;
        float v = (vals[p] - mu) * inv;
        act[l] = (_Float16)(v > 0.f ? v : 0.f);
    }
}

// ---------------- K2: materialize K patch bank kp[n][l][160] ----------------
// grid (8 heads, 64 image rows); block writes 64 pixels x 160 d = 1280 half8
__global__ __launch_bounds__(256) void build_kp(
    const _Float16* __restrict__ k_act, _Float16* __restrict__ kp)
{
    const int n = blockIdx.x, y = blockIdx.y;
    const int tid = threadIdx.x;
    const _Float16* ka = k_act + (size_t)n * 16 * LL;
    _Float16* base = kp + ((size_t)n * LL + y * 64) * DD;
#pragma unroll
    for (int i = 0; i < 5; ++i) {
        int idx = tid + i * 256;          // half8 chunk index within tile
        int x = idx / 20, c20 = idx - x * 20;
        half8 v8;
#pragma unroll
        for (int j = 0; j < 8; ++j) {
            int d = c20 * 8 + j;
            _Float16 v = (_Float16)0.f;
            if (d < 144) {
                int ah = d / 9, t = d - ah * 9;
                int ty = t / 3, tx = t - ty * 3;
                int yy = y + 2 * (ty - 1);
                int xx = x + 2 * (tx - 1);
                if (yy >= 0 && yy <= 63 && xx >= 0 && xx <= 63)
                    v = ka[ah * LL + yy * 64 + xx];
            }
            v8[j] = v;
        }
        *(half8*)(base + (size_t)idx * 8) = v8;
    }
}

// ---------------- K3: zero att accumulator ----------------
__global__ __launch_bounds__(256) void zero_att(float* __restrict__ att)
{
    int idx = blockIdx.x * 256 + threadIdx.x;
    att[idx] = 0.f;
}

// ---------------- K4: flash patch-correlation attention ----------------
// grid = (8 heads, 64 pixel-row tiles) — head fastest for XCD L2 locality.
// 256 threads (4 waves); wave w owns query pixels x in [16w, 16w+16) of row y=qt.
__global__ __launch_bounds__(256) void attn_kernel(
    const _Float16* __restrict__ q_act, const _Float16* __restrict__ kp,
    const _Float16* __restrict__ vb, float* __restrict__ att)
{
    const int n = blockIdx.x, qt = blockIdx.y;
    const int i0 = qt * 64;
    const int tid = threadIdx.x;
    const int w = tid >> 6, lane = tid & 63;
    const int l15 = lane & 15, quad = lane >> 4;

    __shared__ __align__(16) _Float16 BkD[2][64 * BSTR];  // 2 x 21504 B
    __shared__ __align__(16) _Float16 VtD[2][64 * VSTR];  // 2 x  9216 B
    __shared__ __align__(16) _Float16 Pb[4][16 * VSTR];   //      9216 B

    const _Float16* kpn = kp + (size_t)n * LL * DD;
    const uint4* vbu = (const uint4*)vb;

    // staging chunk coords (constant per thread)
    int bx[5], bc[5];
#pragma unroll
    for (int i = 0; i < 5; ++i) {
        int idx = tid + i * 256;
        bx[i] = idx / 20; bc[i] = idx - bx[i] * 20;
    }
    const int vc0 = tid >> 3, ve0 = tid & 7;          // i=0
    const int vc1 = (tid + 256) >> 3, ve1 = tid & 7;  // i=1

    // A-fragments: query pixel (y=qt, x=w*16+l15), d-slice ks*32 + quad*8 (+j)
    half8 afrag[5];
    {
        const _Float16* qa = q_act + (size_t)n * 16 * LL;
        const int x = w * 16 + l15;
#pragma unroll
        for (int ks = 0; ks < 5; ++ks) {
#pragma unroll
            for (int j = 0; j < 8; ++j) {
                int d = ks * 32 + quad * 8 + j;
                _Float16 v = (_Float16)0.f;
                if (d < 144) {
                    int ah = d / 9, t = d - ah * 9;
                    int ty = t / 3, tx = t - ty * 3;
                    int yy = qt + 2 * (ty - 1);
                    int xx = x + 2 * (tx - 1);
                    if (yy >= 0 && yy <= 63 && xx >= 0 && xx <= 63)
                        v = qa[ah * LL + yy * 64 + xx];
                }
                afrag[ks][j] = v;
            }
        }
    }

    floatx4 accO[4];
    float mrow[4], lrow[4];
#pragma unroll
    for (int i = 0; i < 4; ++i) {
        accO[i] = (floatx4){0.f, 0.f, 0.f, 0.f};
        mrow[i] = -1e30f; lrow[i] = 0.f;
    }

    uint4 breg[5], vreg[2];
    // prologue: stage tile 0 into buffer 0
    {
        const uint4* src = (const uint4*)kpn;
#pragma unroll
        for (int i = 0; i < 5; ++i) breg[i] = src[tid + i * 256];
        vreg[0] = vbu[vc0 * (LL / 8) + ve0];
        vreg[1] = vbu[vc1 * (LL / 8) + ve1];
        uint4* bd = (uint4*)BkD[0];
        uint4* vd = (uint4*)VtD[0];
#pragma unroll
        for (int i = 0; i < 5; ++i) bd[bx[i] * 21 + bc[i]] = breg[i];
        vd[vc0 * 9 + ve0] = vreg[0];
        vd[vc1 * 9 + ve1] = vreg[1];
    }
    __syncthreads();

    for (int jt = 0; jt < 64; ++jt) {
        const int p = jt & 1;
        const _Float16* Bk = BkD[p];
        const _Float16* Vt = VtD[p];

        // prefetch tile jt+1 into registers (lands during compute)
        if (jt < 63) {
            const uint4* src = (const uint4*)(kpn + (size_t)(jt + 1) * 64 * DD);
#pragma unroll
            for (int i = 0; i < 5; ++i) breg[i] = src[tid + i * 256];
            vreg[0] = vbu[vc0 * (LL / 8) + (jt + 1) * 8 + ve0];
            vreg[1] = vbu[vc1 * (LL / 8) + (jt + 1) * 8 + ve1];
        }

        // S tile: wave's 16 query pixels x 64 keys, K = 160 (tail zero)
        floatx4 accS[4];
#pragma unroll
        for (int i = 0; i < 4; ++i) accS[i] = (floatx4){0.f, 0.f, 0.f, 0.f};
        for (int ks = 0; ks < 5; ++ks) {
#pragma unroll
            for (int nt = 0; nt < 4; ++nt) {
                half8 bfr = *(const half8*)(Bk + (nt * 16 + l15) * BSTR + ks * 32 + quad * 8);
                accS[nt] = __builtin_amdgcn_mfma_f32_16x16x32_f16(afrag[ks], bfr, accS[nt], 0, 0, 0);
            }
        }

        // online softmax; D-layout: row = quad*4+r, col = l15
#pragma unroll
        for (int r = 0; r < 4; ++r) {
            float tm = fmaxf(fmaxf(accS[0][r], accS[1][r]), fmaxf(accS[2][r], accS[3][r]));
#pragma unroll
            for (int off = 8; off; off >>= 1) tm = fmaxf(tm, __shfl_xor(tm, off, 16));
            float mn = fmaxf(mrow[r], tm);
            float alpha = __expf(mrow[r] - mn);
            mrow[r] = mn;
            float rs = 0.f;
#pragma unroll
            for (int nt = 0; nt < 4; ++nt) {
                float pv = __expf(accS[nt][r] - mn);
                accS[nt][r] = pv;
                rs += pv;
            }
#pragma unroll
            for (int off = 8; off; off >>= 1) rs += __shfl_xor(rs, off, 16);
            lrow[r] = lrow[r] * alpha + rs;
#pragma unroll
            for (int nt = 0; nt < 4; ++nt) accO[nt][r] *= alpha;
        }

        // P: C-layout -> A-layout round trip via per-wave LDS buffer (no barrier:
        // Pb[w] is private to wave w; compiler orders ds_write->ds_read via lgkmcnt)
        _Float16* pw = Pb[w];
#pragma unroll
        for (int nt = 0; nt < 4; ++nt)
#pragma unroll
            for (int r = 0; r < 4; ++r)
                pw[(quad * 4 + r) * VSTR + nt * 16 + l15] = (_Float16)accS[nt][r];

        // O += P @ Vt^T  (K = 64 keys, N = 64 channels)
#pragma unroll
        for (int ks = 0; ks < 2; ++ks) {
            half8 afr = *(const half8*)(pw + l15 * VSTR + ks * 32 + quad * 8);
#pragma unroll
            for (int nt = 0; nt < 4; ++nt) {
                half8 bfr = *(const half8*)(Vt + (nt * 16 + l15) * VSTR + ks * 32 + quad * 8);
                accO[nt] = __builtin_amdgcn_mfma_f32_16x16x32_f16(afr, bfr, accO[nt], 0, 0, 0);
            }
        }

        // stage prefetched tile into the other buffer, then one barrier
        if (jt < 63) {
            uint4* bd = (uint4*)BkD[p ^ 1];
            uint4* vd = (uint4*)VtD[p ^ 1];
#pragma unroll
            for (int i = 0; i < 5; ++i) bd[bx[i] * 21 + bc[i]] = breg[i];
            vd[vc0 * 9 + ve0] = vreg[0];
            vd[vc1 * 9 + ve1] = vreg[1];
        }
        __syncthreads();
    }

    // head-mean accumulate: att[l][c] += O[l][c]/lrow/8
#pragma unroll
    for (int r = 0; r < 4; ++r) {
        float sc = 0.125f / lrow[r];
        int l = i0 + w * 16 + quad * 4 + r;
#pragma unroll
        for (int nt = 0; nt < 4; ++nt)
            atomicAdd(att + (size_t)l * CC + nt * 16 + l15, accO[nt][r] * sc);
    }
}

// ---------------- K5: Wo conv + inorm + relu ----------------
__global__ __launch_bounds__(256) void out_kernel(
    const float* __restrict__ att,
    const float* __restrict__ Wo, const float* __restrict__ bo,
    float* __restrict__ out)
{
    const int o = blockIdx.x;
    const int tid = threadIdx.x;
    __shared__ float sW[CC];
    __shared__ float sm[8];
    if (tid < CC) sW[tid] = Wo[o * CC + tid];
    __syncthreads();
    const float bias = bo[o];

    float vals[16], s1 = 0.f, s2 = 0.f;
    for (int p = 0; p < 16; ++p) {
        int l = p * 256 + tid;
        const float4* arow = (const float4*)(att + (size_t)l * CC);
        float acc = bias;
#pragma unroll
        for (int c4 = 0; c4 < 16; ++c4) {
            float4 a4 = arow[c4];
            acc += sW[c4 * 4] * a4.x + sW[c4 * 4 + 1] * a4.y +
                   sW[c4 * 4 + 2] * a4.z + sW[c4 * 4 + 3] * a4.w;
        }
        vals[p] = acc; s1 += acc; s2 += acc * acc;
    }
    for (int off = 32; off; off >>= 1) {
        s1 += __shfl_down(s1, off, 64);
        s2 += __shfl_down(s2, off, 64);
    }
    int wv = tid >> 6, ln = tid & 63;
    if (ln == 0) { sm[wv * 2] = s1; sm[wv * 2 + 1] = s2; }
    __syncthreads();
    s1 = sm[0] + sm[2] + sm[4] + sm[6];
    s2 = sm[1] + sm[3] + sm[5] + sm[7];
    float mu = s1 * (1.f / LL);
    float inv = rsqrtf(s2 * (1.f / LL) - mu * mu + 1e-5f);
    for (int p = 0; p < 16; ++p) {
        int l = p * 256 + tid;
        float v = (vals[p] - mu) * inv;
        out[(size_t)o * LL + l] = v > 0.f ? v : 0.f;
    }
}

extern "C" void kernel_launch(void* const* d_in, const int* in_sizes, int n_in,
                              void* d_out, int out_size, void* d_ws, size_t ws_size,
                              hipStream_t stream) {
    const float* feat  = (const float*)d_in[0];
    const float* masks = (const float*)d_in[1];
    const float* Wq    = (const float*)d_in[2];
    const float* bq    = (const float*)d_in[3];
    const float* Wk    = (const float*)d_in[4];
    const float* bk    = (const float*)d_in[5];
    const float* Wo    = (const float*)d_in[6];
    const float* bo    = (const float*)d_in[7];
    float* out = (float*)d_out;

    char* ws = (char*)d_ws;
    // layout (bytes) — total 14,155,776 (~13.5 MB):
    //   q_act f16 [128][4096]     @ 0         (1,048,576)
    //   k_act f16 [128][4096]     @ 1,048,576 (1,048,576)
    //   vb    f16 [64][4096]      @ 2,097,152 (  524,288)
    //   att   f32 [4096][64]      @ 2,621,440 (1,048,576)
    //   kp    f16 [8][4096][160]  @ 3,670,016 (10,485,760)
    _Float16* q_act = (_Float16*)ws;
    _Float16* k_act = (_Float16*)(ws + 1048576);
    _Float16* vb    = (_Float16*)(ws + 2097152);
    float*    att   = (float*)(ws + 2621440);
    _Float16* kp    = (_Float16*)(ws + 3670016);

    prep_kernel<<<2 * AA + CC, 256, 0, stream>>>(feat, masks, Wq, bq, Wk, bk,
                                                 q_act, k_act, vb);
    dim3 gb(NH_, 64);
    build_kp<<<gb, 256, 0, stream>>>(k_act, kp);
    zero_att<<<LL * CC / 256, 256, 0, stream>>>(att);
    dim3 g(NH_, 64);
    attn_kernel<<<g, 256, 0, stream>>>(q_act, kp, vb, att);
    out_kernel<<<CC, 256, 0, stream>>>(att, Wo, bo, out);
}

// Round 6
// 405.664 us; speedup vs baseline: 2.2431x; 1.3602x over previous
//
#include <hip/hip_runtime.h>
#include <hip/hip_bf16.h>

// StructureBuilder: masked patch-correlation attention. FP32 I/O, f16 internal.
//   prep:     conv1x1+inorm+relu -> q_act/k_act f16 images; vbar = tap-mean of V
//   build_kp: materialize K patch bank once (f16 [8][4096][160])
//   attn:     flash attention, key-split x2 -> normalized partials + (m,l)
//   combine:  flash-merge halves + head-mean -> att
//   out:      Wo conv + inorm + relu -> fp32

#define LL 4096          // H*W
#define CC 64            // channels
#define AA 128           // attention channels
#define NH_ 8            // heads
#define DD 160           // patch depth 144 padded to 160
#define BSTR 168         // LDS row stride for Bk (21 x 16B)
#define VSTR 72          // LDS row stride for Vt/Pb (9 x 16B)

typedef _Float16 half8 __attribute__((ext_vector_type(8)));
typedef float floatx4 __attribute__((ext_vector_type(4)));

// ---------------- K1: conv1x1 + inorm + relu -> activation images; vbar ----------------
__global__ __launch_bounds__(256) void prep_kernel(
    const float* __restrict__ feat,
    const float* __restrict__ masks,
    const float* __restrict__ Wq, const float* __restrict__ bq,
    const float* __restrict__ Wk, const float* __restrict__ bk,
    _Float16* __restrict__ q_act, _Float16* __restrict__ k_act,
    _Float16* __restrict__ vb)
{
    const int tid = threadIdx.x;
    const int b = blockIdx.x;
    __shared__ float sW[CC];
    __shared__ float sm[8];

    if (b >= 2 * AA) {
        // vbar[c][l] = (1/9) sum_taps f_unmasked[c, l + shift_t]  (OOB = 0)
        int c = b - 2 * AA;
        for (int p = 0; p < 16; ++p) {
            int l = p * 256 + tid;
            int y = l >> 6, x = l & 63;
            float s = 0.f;
            for (int ty = 0; ty < 3; ++ty) {
                int yy = y + 2 * (ty - 1);
                if (yy < 0 || yy > 63) continue;
                for (int tx = 0; tx < 3; ++tx) {
                    int xx = x + 2 * (tx - 1);
                    if (xx < 0 || xx > 63) continue;
                    int ll = yy * 64 + xx;
                    float hole = masks[ll] > 0.5f ? 1.f : 0.f;
                    s += feat[c * LL + ll] * (1.f - hole);
                }
            }
            vb[c * LL + l] = (_Float16)(s * (1.f / 9.f));
        }
        return;
    }

    const int a = b & (AA - 1);
    const int sel = b >> 7;  // 0 = q (hole pixels), 1 = k (unmasked pixels)
    const float* Wrow = (sel ? Wk : Wq) + a * CC;
    const float bias = sel ? bk[a] : bq[a];
    if (tid < CC) sW[tid] = Wrow[tid];
    __syncthreads();

    // conv: c-outer, pixel-inner (1 LDS read per 16 FMAs, 16-wide load ILP)
    float acc[16];
#pragma unroll
    for (int p = 0; p < 16; ++p) acc[p] = 0.f;
    for (int c = 0; c < CC; ++c) {
        float wc = sW[c];
        const float* fr = feat + (size_t)c * LL + tid;
#pragma unroll
        for (int p = 0; p < 16; ++p) acc[p] += wc * fr[p * 256];
    }

    float vals[16];
    float s1 = 0.f, s2 = 0.f;
#pragma unroll
    for (int p = 0; p < 16; ++p) {
        int l = p * 256 + tid;
        float hole = masks[l] > 0.5f ? 1.f : 0.f;
        float mf = sel ? (1.f - hole) : hole;
        float v = acc[p] * mf + bias;
        vals[p] = v; s1 += v; s2 += v * v;
    }
    for (int off = 32; off; off >>= 1) {
        s1 += __shfl_down(s1, off, 64);
        s2 += __shfl_down(s2, off, 64);
    }
    int wv = tid >> 6, ln = tid & 63;
    if (ln == 0) { sm[wv * 2] = s1; sm[wv * 2 + 1] = s2; }
    __syncthreads();
    s1 = sm[0] + sm[2] + sm[4] + sm[6];
    s2 = sm[1] + sm[3] + sm[5] + sm[7];
    float mu = s1 * (1.f / LL);
    float inv = rsqrtf(s2 * (1.f / LL) - mu * mu + 1e-5f);

    _Float16* act = (sel ? k_act : q_act) + (size_t)a * LL;
#pragma unroll
    for (int p = 0; p < 16; ++p) {
        int l = p * 256 + tid;
        float v = (vals[p] - mu) * inv;
        act[l] = (_Float16)(v > 0.f ? v : 0.f);
    }
}

// ---------------- K2: materialize K patch bank kp[n][l][160] ----------------
__global__ __launch_bounds__(256) void build_kp(
    const _Float16* __restrict__ k_act, _Float16* __restrict__ kp)
{
    const int n = blockIdx.x, y = blockIdx.y;
    const int tid = threadIdx.x;
    const _Float16* ka = k_act + (size_t)n * 16 * LL;
    _Float16* base = kp + ((size_t)n * LL + y * 64) * DD;
#pragma unroll
    for (int i = 0; i < 5; ++i) {
        int idx = tid + i * 256;          // half8 chunk index within tile
        int x = idx / 20, c20 = idx - x * 20;
        half8 v8;
#pragma unroll
        for (int j = 0; j < 8; ++j) {
            int d = c20 * 8 + j;
            _Float16 v = (_Float16)0.f;
            if (d < 144) {
                int ah = d / 9, t = d - ah * 9;
                int ty = t / 3, tx = t - ty * 3;
                int yy = y + 2 * (ty - 1);
                int xx = x + 2 * (tx - 1);
                if (yy >= 0 && yy <= 63 && xx >= 0 && xx <= 63)
                    v = ka[ah * LL + yy * 64 + xx];
            }
            v8[j] = v;
        }
        *(half8*)(base + (size_t)idx * 8) = v8;
    }
}

// ---------------- K3: flash attention, key-split x2 ----------------
// grid = (8 heads, 64 q-row tiles, 2 key halves); 256 threads (4 waves).
// LDS 39,936 B -> 4 blocks/CU; single-buffered, register prefetch.
__global__ __launch_bounds__(256, 4) void attn_kernel(
    const _Float16* __restrict__ q_act, const _Float16* __restrict__ kp,
    const _Float16* __restrict__ vb,
    _Float16* __restrict__ Opart, float* __restrict__ ml)
{
    const int n = blockIdx.x, qt = blockIdx.y, h = blockIdx.z;
    const int i0 = qt * 64;
    const int jt0 = h * 32;
    const int tid = threadIdx.x;
    const int w = tid >> 6, lane = tid & 63;
    const int l15 = lane & 15, quad = lane >> 4;

    __shared__ __align__(16) _Float16 Bk[64 * BSTR];    // 21504 B
    __shared__ __align__(16) _Float16 Vt[64 * VSTR];    //  9216 B
    __shared__ __align__(16) _Float16 Pb[4][16 * VSTR]; //  9216 B

    const _Float16* kpn = kp + (size_t)n * LL * DD;
    const uint4* vbu = (const uint4*)vb;

    // staging chunk coords (constant per thread)
    int bx[5], bc[5];
#pragma unroll
    for (int i = 0; i < 5; ++i) {
        int idx = tid + i * 256;
        bx[i] = idx / 20; bc[i] = idx - bx[i] * 20;
    }
    const int vc0 = tid >> 3, ve0 = tid & 7;
    const int vc1 = (tid + 256) >> 3, ve1 = tid & 7;

    // A-fragments: query pixel (y=qt, x=w*16+l15), d-slice ks*32 + quad*8 (+j)
    half8 afrag[5];
    {
        const _Float16* qa = q_act + (size_t)n * 16 * LL;
        const int x = w * 16 + l15;
#pragma unroll
        for (int ks = 0; ks < 5; ++ks) {
#pragma unroll
            for (int j = 0; j < 8; ++j) {
                int d = ks * 32 + quad * 8 + j;
                _Float16 v = (_Float16)0.f;
                if (d < 144) {
                    int ah = d / 9, t = d - ah * 9;
                    int ty = t / 3, tx = t - ty * 3;
                    int yy = qt + 2 * (ty - 1);
                    int xx = x + 2 * (tx - 1);
                    if (yy >= 0 && yy <= 63 && xx >= 0 && xx <= 63)
                        v = qa[ah * LL + yy * 64 + xx];
                }
                afrag[ks][j] = v;
            }
        }
    }

    floatx4 accO[4];
    float mrow[4], lrow[4];
#pragma unroll
    for (int i = 0; i < 4; ++i) {
        accO[i] = (floatx4){0.f, 0.f, 0.f, 0.f};
        mrow[i] = -1e30f; lrow[i] = 0.f;
    }

    uint4 breg[5], vreg[2];
    {   // prologue: load tile jt0 into registers
        const uint4* src = (const uint4*)(kpn + (size_t)jt0 * 64 * DD);
#pragma unroll
        for (int i = 0; i < 5; ++i) breg[i] = src[tid + i * 256];
        vreg[0] = vbu[vc0 * (LL / 8) + jt0 * 8 + ve0];
        vreg[1] = vbu[vc1 * (LL / 8) + jt0 * 8 + ve1];
    }

    for (int it = 0; it < 32; ++it) {
        __syncthreads();  // prior compute's LDS reads complete
        {   // commit registers -> LDS
            uint4* bd = (uint4*)Bk;
            uint4* vd = (uint4*)Vt;
#pragma unroll
            for (int i = 0; i < 5; ++i) bd[bx[i] * 21 + bc[i]] = breg[i];
            vd[vc0 * 9 + ve0] = vreg[0];
            vd[vc1 * 9 + ve1] = vreg[1];
        }
        // prefetch next tile into registers (lands during compute phase)
        if (it < 31) {
            const int jn = jt0 + it + 1;
            const uint4* src = (const uint4*)(kpn + (size_t)jn * 64 * DD);
#pragma unroll
            for (int i = 0; i < 5; ++i) breg[i] = src[tid + i * 256];
            vreg[0] = vbu[vc0 * (LL / 8) + jn * 8 + ve0];
            vreg[1] = vbu[vc1 * (LL / 8) + jn * 8 + ve1];
        }
        __syncthreads();  // staged tile visible

        // S tile: wave's 16 query pixels x 64 keys, K = 160 (tail zero)
        floatx4 accS[4];
#pragma unroll
        for (int i = 0; i < 4; ++i) accS[i] = (floatx4){0.f, 0.f, 0.f, 0.f};
        for (int ks = 0; ks < 5; ++ks) {
#pragma unroll
            for (int nt = 0; nt < 4; ++nt) {
                half8 bfr = *(const half8*)(Bk + (nt * 16 + l15) * BSTR + ks * 32 + quad * 8);
                accS[nt] = __builtin_amdgcn_mfma_f32_16x16x32_f16(afrag[ks], bfr, accS[nt], 0, 0, 0);
            }
        }

        // online softmax; D-layout: row = quad*4+r, col = l15
#pragma unroll
        for (int r = 0; r < 4; ++r) {
            float tm = fmaxf(fmaxf(accS[0][r], accS[1][r]), fmaxf(accS[2][r], accS[3][r]));
#pragma unroll
            for (int off = 8; off; off >>= 1) tm = fmaxf(tm, __shfl_xor(tm, off, 16));
            float mn = fmaxf(mrow[r], tm);
            float alpha = __expf(mrow[r] - mn);
            mrow[r] = mn;
            float rs = 0.f;
#pragma unroll
            for (int nt = 0; nt < 4; ++nt) {
                float pv = __expf(accS[nt][r] - mn);
                accS[nt][r] = pv;
                rs += pv;
            }
#pragma unroll
            for (int off = 8; off; off >>= 1) rs += __shfl_xor(rs, off, 16);
            lrow[r] = lrow[r] * alpha + rs;
#pragma unroll
            for (int nt = 0; nt < 4; ++nt) accO[nt][r] *= alpha;
        }

        // P: C-layout -> A-layout via per-wave LDS buffer, XOR-swizzled
        // (key-block col' = nt ^ quad breaks the 4-way quad bank collision)
        _Float16* pw = Pb[w];
#pragma unroll
        for (int nt = 0; nt < 4; ++nt)
#pragma unroll
            for (int r = 0; r < 4; ++r)
                pw[(quad * 4 + r) * VSTR + ((nt ^ quad) << 4) + l15] = (_Float16)accS[nt][r];

        // O += P @ Vt^T  (K = 64 keys, N = 64 channels)
#pragma unroll
        for (int ks = 0; ks < 2; ++ks) {
            int kb = ks * 2 + (quad >> 1);  // key 16-block of this lane's slice
            half8 afr = *(const half8*)(pw + l15 * VSTR + ((kb ^ (l15 >> 2)) << 4) + (quad & 1) * 8);
#pragma unroll
            for (int nt = 0; nt < 4; ++nt) {
                half8 bfr = *(const half8*)(Vt + (nt * 16 + l15) * VSTR + ks * 32 + quad * 8);
                accO[nt] = __builtin_amdgcn_mfma_f32_16x16x32_f16(afr, bfr, accO[nt], 0, 0, 0);
            }
        }
    }

    // epilogue: normalized partial (f16) + (m,l) per q-row
    _Float16* op = Opart + ((size_t)(n * 2 + h) * LL + i0 + w * 16) * CC;
#pragma unroll
    for (int r = 0; r < 4; ++r) {
        float invl = 1.f / lrow[r];
        int row = quad * 4 + r;
#pragma unroll
        for (int nt = 0; nt < 4; ++nt)
            op[row * CC + nt * 16 + l15] = (_Float16)(accO[nt][r] * invl);
        if (l15 == 0) {
            float* mlp = ml + ((size_t)n * LL + i0 + w * 16 + row) * 4;
            mlp[2 * h] = mrow[r];
            mlp[2 * h + 1] = lrow[r];
        }
    }
}

// ---------------- K4: flash-merge halves + head-mean ----------------
__global__ __launch_bounds__(256) void combine_kernel(
    const _Float16* __restrict__ Opart, const float* __restrict__ ml,
    float* __restrict__ att)
{
    int t = blockIdx.x * 256 + threadIdx.x;   // 0 .. LL*CC-1
    int l = t >> 6, c = t & 63;
    float s = 0.f;
#pragma unroll
    for (int n = 0; n < NH_; ++n) {
        const float* mlp = ml + ((size_t)n * LL + l) * 4;
        float m0 = mlp[0], l0 = mlp[1], m1 = mlp[2], l1 = mlp[3];
        float M = fmaxf(m0, m1);
        float w0 = l0 * __expf(m0 - M);
        float w1 = l1 * __expf(m1 - M);
        float o0 = (float)Opart[((size_t)(2 * n) * LL + l) * CC + c];
        float o1 = (float)Opart[((size_t)(2 * n + 1) * LL + l) * CC + c];
        s += (w0 * o0 + w1 * o1) / (w0 + w1);
    }
    att[t] = s * 0.125f;
}

// ---------------- K5: Wo conv + inorm + relu ----------------
__global__ __launch_bounds__(256) void out_kernel(
    const float* __restrict__ att,
    const float* __restrict__ Wo, const float* __restrict__ bo,
    float* __restrict__ out)
{
    const int o = blockIdx.x;
    const int tid = threadIdx.x;
    __shared__ float sW[CC];
    __shared__ float sm[8];
    if (tid < CC) sW[tid] = Wo[o * CC + tid];
    __syncthreads();
    const float bias = bo[o];

    float vals[16], s1 = 0.f, s2 = 0.f;
    for (int p = 0; p < 16; ++p) {
        int l = p * 256 + tid;
        const float4* arow = (const float4*)(att + (size_t)l * CC);
        float acc = bias;
#pragma unroll
        for (int c4 = 0; c4 < 16; ++c4) {
            float4 a4 = arow[c4];
            acc += sW[c4 * 4] * a4.x + sW[c4 * 4 + 1] * a4.y +
                   sW[c4 * 4 + 2] * a4.z + sW[c4 * 4 + 3] * a4.w;
        }
        vals[p] = acc; s1 += acc; s2 += acc * acc;
    }
    for (int off = 32; off; off >>= 1) {
        s1 += __shfl_down(s1, off, 64);
        s2 += __shfl_down(s2, off, 64);
    }
    int wv = tid >> 6, ln = tid & 63;
    if (ln == 0) { sm[wv * 2] = s1; sm[wv * 2 + 1] = s2; }
    __syncthreads();
    s1 = sm[0] + sm[2] + sm[4] + sm[6];
    s2 = sm[1] + sm[3] + sm[5] + sm[7];
    float mu = s1 * (1.f / LL);
    float inv = rsqrtf(s2 * (1.f / LL) - mu * mu + 1e-5f);
    for (int p = 0; p < 16; ++p) {
        int l = p * 256 + tid;
        float v = (vals[p] - mu) * inv;
        out[(size_t)o * LL + l] = v > 0.f ? v : 0.f;
    }
}

extern "C" void kernel_launch(void* const* d_in, const int* in_sizes, int n_in,
                              void* d_out, int out_size, void* d_ws, size_t ws_size,
                              hipStream_t stream) {
    const float* feat  = (const float*)d_in[0];
    const float* masks = (const float*)d_in[1];
    const float* Wq    = (const float*)d_in[2];
    const float* bq    = (const float*)d_in[3];
    const float* Wk    = (const float*)d_in[4];
    const float* bk    = (const float*)d_in[5];
    const float* Wo    = (const float*)d_in[6];
    const float* bo    = (const float*)d_in[7];
    float* out = (float*)d_out;

    char* ws = (char*)d_ws;
    // layout (bytes) — total 23,068,672 (~22 MB):
    //   q_act f16 [128][4096]       @ 0          (1,048,576)
    //   k_act f16 [128][4096]       @ 1,048,576  (1,048,576)
    //   vb    f16 [64][4096]        @ 2,097,152  (  524,288)
    //   att   f32 [4096][64]        @ 2,621,440  (1,048,576)
    //   kp    f16 [8][4096][160]    @ 3,670,016  (10,485,760)
    //   Opart f16 [16][4096][64]    @ 14,155,776 (8,388,608)
    //   ml    f32 [8][4096][4]      @ 22,544,384 (  524,288)
    _Float16* q_act = (_Float16*)ws;
    _Float16* k_act = (_Float16*)(ws + 1048576);
    _Float16* vb    = (_Float16*)(ws + 2097152);
    float*    att   = (float*)(ws + 2621440);
    _Float16* kp    = (_Float16*)(ws + 3670016);
    _Float16* Opart = (_Float16*)(ws + 14155776);
    float*    ml    = (float*)(ws + 22544384);

    prep_kernel<<<2 * AA + CC, 256, 0, stream>>>(feat, masks, Wq, bq, Wk, bk,
                                                 q_act, k_act, vb);
    dim3 gb(NH_, 64);
    build_kp<<<gb, 256, 0, stream>>>(k_act, kp);
    dim3 g(NH_, 64, 2);
    attn_kernel<<<g, 256, 0, stream>>>(q_act, kp, vb, Opart, ml);
    combine_kernel<<<LL * CC / 256, 256, 0, stream>>>(Opart, ml, att);
    out_kernel<<<CC, 256, 0, stream>>>(att, Wo, bo, out);
}

// Round 7
// 290.235 us; speedup vs baseline: 3.1352x; 1.3977x over previous
//
#include <hip/hip_runtime.h>
#include <hip/hip_bf16.h>

// StructureBuilder: masked patch-correlation attention. FP32 I/O, f16 internal.
//   prep:     conv1x1+inorm+relu -> q_act/k_act f16 images; vbar = tap-mean of V
//   build_kp: materialize K patch bank, row stride 168 (21x16B -> global_load_lds
//             tiles are 21 contiguous 1024B wave-chunks; 2-way LDS bank aliasing)
//   attn:     flash attention, key-split x2; Bk staged via async global->LDS DMA
//   combine:  flash-merge halves + head-mean -> att
//   out:      Wo conv + inorm + relu -> fp32

#define LL 4096          // H*W
#define CC 64            // channels
#define AA 128           // attention channels
#define NH_ 8            // heads
#define KSTR 168         // kp row stride (f16): 144 data + pad; 21 x 8 halves
#define VSTR 72          // LDS row stride for Vt/Pb (9 x 16B)

typedef _Float16 half8 __attribute__((ext_vector_type(8)));
typedef float floatx4 __attribute__((ext_vector_type(4)));

// ---------------- K1: conv1x1 + inorm + relu -> activation images; vbar ----------------
__global__ __launch_bounds__(256) void prep_kernel(
    const float* __restrict__ feat,
    const float* __restrict__ masks,
    const float* __restrict__ Wq, const float* __restrict__ bq,
    const float* __restrict__ Wk, const float* __restrict__ bk,
    _Float16* __restrict__ q_act, _Float16* __restrict__ k_act,
    _Float16* __restrict__ vb)
{
    const int tid = threadIdx.x;
    const int b = blockIdx.x;
    __shared__ float sW[CC];
    __shared__ float sm[8];

    if (b >= 2 * AA) {
        // vbar[c][l] = (1/9) sum_taps f_unmasked[c, l + shift_t]  (OOB = 0)
        int c = b - 2 * AA;
        for (int p = 0; p < 16; ++p) {
            int l = p * 256 + tid;
            int y = l >> 6, x = l & 63;
            float s = 0.f;
            for (int ty = 0; ty < 3; ++ty) {
                int yy = y + 2 * (ty - 1);
                if (yy < 0 || yy > 63) continue;
                for (int tx = 0; tx < 3; ++tx) {
                    int xx = x + 2 * (tx - 1);
                    if (xx < 0 || xx > 63) continue;
                    int ll = yy * 64 + xx;
                    float hole = masks[ll] > 0.5f ? 1.f : 0.f;
                    s += feat[c * LL + ll] * (1.f - hole);
                }
            }
            vb[c * LL + l] = (_Float16)(s * (1.f / 9.f));
        }
        return;
    }

    const int a = b & (AA - 1);
    const int sel = b >> 7;  // 0 = q (hole pixels), 1 = k (unmasked pixels)
    const float* Wrow = (sel ? Wk : Wq) + a * CC;
    const float bias = sel ? bk[a] : bq[a];
    if (tid < CC) sW[tid] = Wrow[tid];
    __syncthreads();

    // conv: c-outer, pixel-inner (1 LDS read per 16 FMAs, 16-wide load ILP)
    float acc[16];
#pragma unroll
    for (int p = 0; p < 16; ++p) acc[p] = 0.f;
    for (int c = 0; c < CC; ++c) {
        float wc = sW[c];
        const float* fr = feat + (size_t)c * LL + tid;
#pragma unroll
        for (int p = 0; p < 16; ++p) acc[p] += wc * fr[p * 256];
    }

    float vals[16];
    float s1 = 0.f, s2 = 0.f;
#pragma unroll
    for (int p = 0; p < 16; ++p) {
        int l = p * 256 + tid;
        float hole = masks[l] > 0.5f ? 1.f : 0.f;
        float mf = sel ? (1.f - hole) : hole;
        float v = acc[p] * mf + bias;
        vals[p] = v; s1 += v; s2 += v * v;
    }
    for (int off = 32; off; off >>= 1) {
        s1 += __shfl_down(s1, off, 64);
        s2 += __shfl_down(s2, off, 64);
    }
    int wv = tid >> 6, ln = tid & 63;
    if (ln == 0) { sm[wv * 2] = s1; sm[wv * 2 + 1] = s2; }
    __syncthreads();
    s1 = sm[0] + sm[2] + sm[4] + sm[6];
    s2 = sm[1] + sm[3] + sm[5] + sm[7];
    float mu = s1 * (1.f / LL);
    float inv = rsqrtf(s2 * (1.f / LL) - mu * mu + 1e-5f);

    _Float16* act = (sel ? k_act : q_act) + (size_t)a * LL;
#pragma unroll
    for (int p = 0; p < 16; ++p) {
        int l = p * 256 + tid;
        float v = (vals[p] - mu) * inv;
        act[l] = (_Float16)(v > 0.f ? v : 0.f);
    }
}

// ---------------- K2: materialize K patch bank kp[n][l][KSTR] ----------------
// grid (8 heads, 64 image rows); tile = 64 pixels x 21 half8 chunks = 1344 chunks
__global__ __launch_bounds__(256) void build_kp(
    const _Float16* __restrict__ k_act, _Float16* __restrict__ kp)
{
    const int n = blockIdx.x, y = blockIdx.y;
    const int tid = threadIdx.x;
    const _Float16* ka = k_act + (size_t)n * 16 * LL;
    _Float16* base = kp + ((size_t)n * LL + y * 64) * KSTR;
#pragma unroll
    for (int i = 0; i < 6; ++i) {
        int idx = tid + i * 256;          // half8 chunk index within tile
        if (idx >= 64 * 21) break;
        int x = idx / 21, c21 = idx - x * 21;
        half8 v8;
#pragma unroll
        for (int j = 0; j < 8; ++j) {
            int d = c21 * 8 + j;
            _Float16 v = (_Float16)0.f;
            if (d < 144) {
                int ah = d / 9, t = d - ah * 9;
                int ty = t / 3, tx = t - ty * 3;
                int yy = y + 2 * (ty - 1);
                int xx = x + 2 * (tx - 1);
                if (yy >= 0 && yy <= 63 && xx >= 0 && xx <= 63)
                    v = ka[ah * LL + yy * 64 + xx];
            }
            v8[j] = v;
        }
        *(half8*)(base + (size_t)idx * 8) = v8;   // rows are exactly 21 chunks
    }
}

// ---------------- K3: flash attention, key-split x2 ----------------
// grid = (8 heads, 64 q-row tiles, 2 key halves); 256 threads (4 waves).
// LDS 39,936 B -> 4 blocks/CU. Bk staged by async global_load_lds (no VGPRs).
__global__ __launch_bounds__(256) void attn_kernel(
    const _Float16* __restrict__ q_act, const _Float16* __restrict__ kp,
    const _Float16* __restrict__ vb,
    _Float16* __restrict__ Opart, float* __restrict__ ml)
{
    const int n = blockIdx.x, qt = blockIdx.y, h = blockIdx.z;
    const int i0 = qt * 64;
    const int jt0 = h * 32;
    const int tid = threadIdx.x;
    const int w = tid >> 6, lane = tid & 63;
    const int l15 = lane & 15, quad = lane >> 4;

    __shared__ __align__(16) _Float16 Bk[64 * KSTR];    // 21504 B
    __shared__ __align__(16) _Float16 Vt[64 * VSTR];    //  9216 B
    __shared__ __align__(16) _Float16 Pb[4][16 * VSTR]; //  9216 B

    const _Float16* kpn = kp + (size_t)n * LL * KSTR;
    const uint4* vbu = (const uint4*)vb;

    const int vc0 = tid >> 3, ve0 = tid & 7;
    const int vc1 = (tid + 256) >> 3, ve1 = tid & 7;

    // async DMA: tile jt -> Bk. 21 chunks of 1024B; wave w takes chunks w, w+4, ...
    auto issue_bk = [&](int jt) {
        const char* tile = (const char*)(kpn + (size_t)jt * 64 * KSTR) + (lane << 4);
        for (int c = w; c < 21; c += 4) {
            __builtin_amdgcn_global_load_lds(
                (const __attribute__((address_space(1))) void*)(tile + c * 1024),
                (__attribute__((address_space(3))) void*)(Bk + c * 512),
                16, 0, 0);
        }
    };

    // A-fragments: query pixel (y=qt, x=w*16+l15), d-slice ks*32 + quad*8 (+j)
    half8 afrag[5];
    {
        const _Float16* qa = q_act + (size_t)n * 16 * LL;
        const int x = w * 16 + l15;
#pragma unroll
        for (int ks = 0; ks < 5; ++ks) {
#pragma unroll
            for (int j = 0; j < 8; ++j) {
                int d = ks * 32 + quad * 8 + j;
                _Float16 v = (_Float16)0.f;
                if (d < 144) {
                    int ah = d / 9, t = d - ah * 9;
                    int ty = t / 3, tx = t - ty * 3;
                    int yy = qt + 2 * (ty - 1);
                    int xx = x + 2 * (tx - 1);
                    if (yy >= 0 && yy <= 63 && xx >= 0 && xx <= 63)
                        v = qa[ah * LL + yy * 64 + xx];
                }
                afrag[ks][j] = v;
            }
        }
    }

    floatx4 accO[4];
    float mrow[4], lrow[4];
#pragma unroll
    for (int i = 0; i < 4; ++i) {
        accO[i] = (floatx4){0.f, 0.f, 0.f, 0.f};
        mrow[i] = -1e30f; lrow[i] = 0.f;
    }

    uint4 vreg[2];
    issue_bk(jt0);                                   // async, in flight
    vreg[0] = vbu[vc0 * (LL / 8) + jt0 * 8 + ve0];
    vreg[1] = vbu[vc1 * (LL / 8) + jt0 * 8 + ve1];

    for (int it = 0; it < 32; ++it) {
        {   // commit Vt registers -> LDS
            uint4* vd = (uint4*)Vt;
            vd[vc0 * 9 + ve0] = vreg[0];
            vd[vc1 * 9 + ve1] = vreg[1];
        }
        __syncthreads();  // drains vmcnt (Bk DMA) + lgkm (Vt writes); tile staged

        // prefetch next Vt tile into registers (overlaps compute)
        if (it < 31) {
            const int jn = jt0 + it + 1;
            vreg[0] = vbu[vc0 * (LL / 8) + jn * 8 + ve0];
            vreg[1] = vbu[vc1 * (LL / 8) + jn * 8 + ve1];
        }

        // S tile: wave's 16 query pixels x 64 keys, K = 160 (tail zero)
        floatx4 accS[4];
#pragma unroll
        for (int i = 0; i < 4; ++i) accS[i] = (floatx4){0.f, 0.f, 0.f, 0.f};
        for (int ks = 0; ks < 5; ++ks) {
#pragma unroll
            for (int nt = 0; nt < 4; ++nt) {
                half8 bfr = *(const half8*)(Bk + (nt * 16 + l15) * KSTR + ks * 32 + quad * 8);
                accS[nt] = __builtin_amdgcn_mfma_f32_16x16x32_f16(afrag[ks], bfr, accS[nt], 0, 0, 0);
            }
        }

        // online softmax; D-layout: row = quad*4+r, col = l15
#pragma unroll
        for (int r = 0; r < 4; ++r) {
            float tm = fmaxf(fmaxf(accS[0][r], accS[1][r]), fmaxf(accS[2][r], accS[3][r]));
#pragma unroll
            for (int off = 8; off; off >>= 1) tm = fmaxf(tm, __shfl_xor(tm, off, 16));
            float mn = fmaxf(mrow[r], tm);
            float alpha = __expf(mrow[r] - mn);
            mrow[r] = mn;
            float rs = 0.f;
#pragma unroll
            for (int nt = 0; nt < 4; ++nt) {
                float pv = __expf(accS[nt][r] - mn);
                accS[nt][r] = pv;
                rs += pv;
            }
#pragma unroll
            for (int off = 8; off; off >>= 1) rs += __shfl_xor(rs, off, 16);
            lrow[r] = lrow[r] * alpha + rs;
#pragma unroll
            for (int nt = 0; nt < 4; ++nt) accO[nt][r] *= alpha;
        }

        // P: C-layout -> A-layout via per-wave LDS buffer, XOR-swizzled
        _Float16* pw = Pb[w];
#pragma unroll
        for (int nt = 0; nt < 4; ++nt)
#pragma unroll
            for (int r = 0; r < 4; ++r)
                pw[(quad * 4 + r) * VSTR + ((nt ^ quad) << 4) + l15] = (_Float16)accS[nt][r];

        // O += P @ Vt^T  (K = 64 keys, N = 64 channels)
#pragma unroll
        for (int ks = 0; ks < 2; ++ks) {
            int kb = ks * 2 + (quad >> 1);
            half8 afr = *(const half8*)(pw + l15 * VSTR + ((kb ^ (l15 >> 2)) << 4) + (quad & 1) * 8);
#pragma unroll
            for (int nt = 0; nt < 4; ++nt) {
                half8 bfr = *(const half8*)(Vt + (nt * 16 + l15) * VSTR + ks * 32 + quad * 8);
                accO[nt] = __builtin_amdgcn_mfma_f32_16x16x32_f16(afr, bfr, accO[nt], 0, 0, 0);
            }
        }

        __syncthreads();  // all waves done reading Bk/Vt
        if (it < 31) issue_bk(jt0 + it + 1);  // refill async
    }

    // epilogue: normalized partial (f16) + (m,l) per q-row
    _Float16* op = Opart + ((size_t)(n * 2 + h) * LL + i0 + w * 16) * CC;
#pragma unroll
    for (int r = 0; r < 4; ++r) {
        float invl = 1.f / lrow[r];
        int row = quad * 4 + r;
#pragma unroll
        for (int nt = 0; nt < 4; ++nt)
            op[row * CC + nt * 16 + l15] = (_Float16)(accO[nt][r] * invl);
        if (l15 == 0) {
            float* mlp = ml + ((size_t)n * LL + i0 + w * 16 + row) * 4;
            mlp[2 * h] = mrow[r];
            mlp[2 * h + 1] = lrow[r];
        }
    }
}

// ---------------- K4: flash-merge halves + head-mean ----------------
__global__ __launch_bounds__(256) void combine_kernel(
    const _Float16* __restrict__ Opart, const float* __restrict__ ml,
    float* __restrict__ att)
{
    int t = blockIdx.x * 256 + threadIdx.x;   // 0 .. LL*CC-1
    int l = t >> 6, c = t & 63;
    float s = 0.f;
#pragma unroll
    for (int n = 0; n < NH_; ++n) {
        const float* mlp = ml + ((size_t)n * LL + l) * 4;
        float m0 = mlp[0], l0 = mlp[1], m1 = mlp[2], l1 = mlp[3];
        float M = fmaxf(m0, m1);
        float w0 = l0 * __expf(m0 - M);
        float w1 = l1 * __expf(m1 - M);
        float o0 = (float)Opart[((size_t)(2 * n) * LL + l) * CC + c];
        float o1 = (float)Opart[((size_t)(2 * n + 1) * LL + l) * CC + c];
        s += (w0 * o0 + w1 * o1) / (w0 + w1);
    }
    att[t] = s * 0.125f;
}

// ---------------- K5: Wo conv + inorm + relu ----------------
__global__ __launch_bounds__(256) void out_kernel(
    const float* __restrict__ att,
    const float* __restrict__ Wo, const float* __restrict__ bo,
    float* __restrict__ out)
{
    const int o = blockIdx.x;
    const int tid = threadIdx.x;
    __shared__ float sW[CC];
    __shared__ float sm[8];
    if (tid < CC) sW[tid] = Wo[o * CC + tid];
    __syncthreads();
    const float bias = bo[o];

    float vals[16], s1 = 0.f, s2 = 0.f;
    for (int p = 0; p < 16; ++p) {
        int l = p * 256 + tid;
        const float4* arow = (const float4*)(att + (size_t)l * CC);
        float acc = bias;
#pragma unroll
        for (int c4 = 0; c4 < 16; ++c4) {
            float4 a4 = arow[c4];
            acc += sW[c4 * 4] * a4.x + sW[c4 * 4 + 1] * a4.y +
                   sW[c4 * 4 + 2] * a4.z + sW[c4 * 4 + 3] * a4.w;
        }
        vals[p] = acc; s1 += acc; s2 += acc * acc;
    }
    for (int off = 32; off; off >>= 1) {
        s1 += __shfl_down(s1, off, 64);
        s2 += __shfl_down(s2, off, 64);
    }
    int wv = tid >> 6, ln = tid & 63;
    if (ln == 0) { sm[wv * 2] = s1; sm[wv * 2 + 1] = s2; }
    __syncthreads();
    s1 = sm[0] + sm[2] + sm[4] + sm[6];
    s2 = sm[1] + sm[3] + sm[5] + sm[7];
    float mu = s1 * (1.f / LL);
    float inv = rsqrtf(s2 * (1.f / LL) - mu * mu + 1e-5f);
    for (int p = 0; p < 16; ++p) {
        int l = p * 256 + tid;
        float v = (vals[p] - mu) * inv;
        out[(size_t)o * LL + l] = v > 0.f ? v : 0.f;
    }
}

extern "C" void kernel_launch(void* const* d_in, const int* in_sizes, int n_in,
                              void* d_out, int out_size, void* d_ws, size_t ws_size,
                              hipStream_t stream) {
    const float* feat  = (const float*)d_in[0];
    const float* masks = (const float*)d_in[1];
    const float* Wq    = (const float*)d_in[2];
    const float* bq    = (const float*)d_in[3];
    const float* Wk    = (const float*)d_in[4];
    const float* bk    = (const float*)d_in[5];
    const float* Wo    = (const float*)d_in[6];
    const float* bo    = (const float*)d_in[7];
    float* out = (float*)d_out;

    char* ws = (char*)d_ws;
    // layout (bytes) — total 23,592,960 (~22.5 MB):
    //   q_act f16 [128][4096]       @ 0          (1,048,576)
    //   k_act f16 [128][4096]       @ 1,048,576  (1,048,576)
    //   vb    f16 [64][4096]        @ 2,097,152  (  524,288)
    //   att   f32 [4096][64]        @ 2,621,440  (1,048,576)
    //   kp    f16 [8][4096][168]    @ 3,670,016  (11,010,048)
    //   Opart f16 [16][4096][64]    @ 14,680,064 (8,388,608)
    //   ml    f32 [8][4096][4]      @ 23,068,672 (  524,288)
    _Float16* q_act = (_Float16*)ws;
    _Float16* k_act = (_Float16*)(ws + 1048576);
    _Float16* vb    = (_Float16*)(ws + 2097152);
    float*    att   = (float*)(ws + 2621440);
    _Float16* kp    = (_Float16*)(ws + 3670016);
    _Float16* Opart = (_Float16*)(ws + 14680064);
    float*    ml    = (float*)(ws + 23068672);

    prep_kernel<<<2 * AA + CC, 256, 0, stream>>>(feat, masks, Wq, bq, Wk, bk,
                                                 q_act, k_act, vb);
    dim3 gb(NH_, 64);
    build_kp<<<gb, 256, 0, stream>>>(k_act, kp);
    dim3 g(NH_, 64, 2);
    attn_kernel<<<g, 256, 0, stream>>>(q_act, kp, vb, Opart, ml);
    combine_kernel<<<LL * CC / 256, 256, 0, stream>>>(Opart, ml, att);
    out_kernel<<<CC, 256, 0, stream>>>(att, Wo, bo, out);
}